// Round 6
// baseline (64.562 us; speedup 1.0000x reference)
//
#include <hip/hip_runtime.h>

// Problem constants (fixed by reference)
constexpr int BSZ = 4, SEQ = 2048, D = 128, H = 4, E = 65536;
constexpr int N  = BSZ * SEQ;   // 8192 nodes
constexpr int HC = H * D;       // 512
constexpr int SLOTS = 128;      // per-dst bucket capacity; in-deg ~ Binom(65536,1/2048), mean 32
constexpr int MAXE  = SLOTS + 4;

typedef __attribute__((ext_vector_type(8))) short s16x8;
typedef __attribute__((ext_vector_type(4))) float f32x4;

__device__ inline unsigned short f2bf(float v) {            // fp32 -> bf16 RNE
    unsigned u = __float_as_uint(v);
    return (unsigned short)((u + 0x7fffu + ((u >> 16) & 1u)) >> 16);
}
__device__ inline float bf2f(unsigned short h) { return __uint_as_float(((unsigned)h) << 16); }

// ================= prep_all: block-specialized =================
// b in [0,256)   : Pcat[d, h*128+k] = sum_c Wo[d,h*128+c] * W[h*128+c, k]
//                  written in MFMA B-fragment-packed order (split bf16)
// b in [256,384) : cvec[d] = sum_j bias[j]*Wo[d,j] + bo[d]
// b in [384,386) : w_src[h,d] = sum_c att_src[h,c]*W[h*128+c, d]  (and w_dst)
// b in [386,394) : zero cursor[0..2047]
__global__ __launch_bounds__(256) void prep_all(const float* __restrict__ W,
                                                const float* __restrict__ att_src,
                                                const float* __restrict__ att_dst,
                                                const float* __restrict__ bias,
                                                const float* __restrict__ Wo,
                                                const float* __restrict__ bo,
                                                float* __restrict__ w_src,
                                                float* __restrict__ w_dst,
                                                unsigned short* __restrict__ p_hi,
                                                unsigned short* __restrict__ p_lo,
                                                float* __restrict__ cvec,
                                                int* __restrict__ cursor) {
    __shared__ float part[4];
    const int b = blockIdx.x, tid = threadIdx.x;
    if (b < 256) {                      // --- prep_P (fragment-packed) ---
        int h = b & 3;
        int d = (b >> 2) * 2 + (tid >> 7);
        int k = tid & 127;
        float acc = 0.f;
        for (int c = 0; c < D; ++c)
            acc += Wo[d * HC + h * D + c] * W[(h * D + c) * D + k];
        unsigned short hi = f2bf(acc);
        // B-fragment packing for mfma_f32_16x16x32_bf16:
        // element (col=d, kglobal=h*128+k) lives at lane=(kin>>3)*16+(d&15), j=kin&7
        int ct = d >> 4, lrow = d & 15;
        int kg = h * D + k, kstep = kg >> 5, kin = kg & 31;
        size_t idx = ((size_t)(ct * 16 + kstep) * 64 + (kin >> 3) * 16 + lrow) * 8 + (kin & 7);
        p_hi[idx] = hi;
        p_lo[idx] = f2bf(acc - bf2f(hi));
    } else if (b < 384) {               // --- prep_c ---
        int d = b - 256;
        float a = bias[tid] * Wo[d * HC + tid] + bias[tid + 256] * Wo[d * HC + tid + 256];
        #pragma unroll
        for (int off = 32; off; off >>= 1) a += __shfl_xor(a, off);
        if ((tid & 63) == 0) part[tid >> 6] = a;
        __syncthreads();
        if (tid == 0) cvec[d] = part[0] + part[1] + part[2] + part[3] + bo[d];
    } else if (b < 386) {               // --- prep_w ---
        int t = (b - 384) * 256 + tid;  // 0..511
        int h = t >> 7, dd = t & 127;
        float ws = 0.f, wd = 0.f;
        for (int c = 0; c < D; ++c) {
            float wv = W[(h * D + c) * D + dd];
            ws += att_src[h * D + c] * wv;
            wd += att_dst[h * D + c] * wv;
        }
        w_src[t] = ws;
        w_dst[t] = wd;
    } else {                            // --- zero cursor ---
        int idx = (b - 386) * 256 + tid;
        if (idx < SEQ) cursor[idx] = 0;
    }
}

// ======== att_fill: a_src/a_dst per node; first 256 blocks also bucket the edges ========
__global__ __launch_bounds__(256) void att_fill(const float* __restrict__ s,
                                                const float* __restrict__ w_src,
                                                const float* __restrict__ w_dst,
                                                const int* __restrict__ ei,
                                                float* __restrict__ a_src,
                                                float* __restrict__ a_dst,
                                                int* __restrict__ cursor,
                                                int* __restrict__ csr0) {
    const int bid = blockIdx.x, tid = threadIdx.x;
    if (bid < 256) {                    // bucket-fill: one edge per thread
        int e = bid * 256 + tid;
        int src = ei[e], dst = ei[E + e];
        int slot = atomicAdd(&cursor[dst], 1);
        if (slot < SLOTS) csr0[dst * SLOTS + slot] = src;
    }
    const int wave = tid >> 6, lane = tid & 63;
    const int n = bid * 4 + wave;
    float s0 = s[n * D + lane];
    float s1 = s[n * D + 64 + lane];
    #pragma unroll
    for (int h = 0; h < H; ++h) {
        float ps = s0 * w_src[h * D + lane] + s1 * w_src[h * D + 64 + lane];
        float pd = s0 * w_dst[h * D + lane] + s1 * w_dst[h * D + 64 + lane];
        #pragma unroll
        for (int off = 32; off; off >>= 1) {
            ps += __shfl_xor(ps, off);
            pd += __shfl_xor(pd, off);
        }
        if (lane == 0) {
            a_src[n * H + h] = ps;
            a_dst[n * H + h] = pd;
        }
    }
}

// ======== per-dst softmax + gather of s rows -> z (split bf16, A-frag-packed) ========
__global__ __launch_bounds__(256) void node_aggregate_z(const int* __restrict__ cursor,
                                                        const int* __restrict__ csr0,
                                                        const float* __restrict__ a_src,
                                                        const float* __restrict__ a_dst,
                                                        const float* __restrict__ s,
                                                        unsigned short* __restrict__ z_hi,
                                                        unsigned short* __restrict__ z_lo) {
    __shared__ float sh_alpha[4][MAXE][4];
    __shared__ int   sh_src[4][MAXE];
    const int wave = threadIdx.x >> 6, lane = threadIdx.x & 63;
    const int n = blockIdx.x * 4 + wave;
    const int b = n >> 11, dloc = n & 2047;
    int deg = cursor[dloc];
    deg = (deg < SLOTS) ? deg : SLOTS;
    const int beg = dloc * SLOTS;
    const int cnt = deg + 1;                      // + self loop
    float4 adv = *reinterpret_cast<const float4*>(&a_dst[n * H]);
    float ad[4] = {adv.x, adv.y, adv.z, adv.w};
    float mx[4] = {-1e30f, -1e30f, -1e30f, -1e30f};
    for (int i = lane; i < cnt; i += 64) {
        int sg = (i < deg) ? (csr0[beg + i] + (b << 11)) : n;
        sh_src[wave][i] = sg;
        float4 asv = *reinterpret_cast<const float4*>(&a_src[sg * H]);
        float lg[4] = {asv.x, asv.y, asv.z, asv.w};
        #pragma unroll
        for (int h = 0; h < 4; ++h) {
            float l = lg[h] + ad[h];
            l = (l > 0.f) ? l : 0.2f * l;
            sh_alpha[wave][i][h] = l;
            mx[h] = fmaxf(mx[h], l);
        }
    }
    #pragma unroll
    for (int h = 0; h < 4; ++h)
        #pragma unroll
        for (int off = 32; off; off >>= 1) mx[h] = fmaxf(mx[h], __shfl_xor(mx[h], off));
    float sm[4] = {0.f, 0.f, 0.f, 0.f};
    for (int i = lane; i < cnt; i += 64) {
        #pragma unroll
        for (int h = 0; h < 4; ++h) {
            float ev = expf(sh_alpha[wave][i][h] - mx[h]);
            sh_alpha[wave][i][h] = ev;
            sm[h] += ev;
        }
    }
    #pragma unroll
    for (int h = 0; h < 4; ++h)
        #pragma unroll
        for (int off = 32; off; off >>= 1) sm[h] += __shfl_xor(sm[h], off);
    __syncthreads();
    float inv[4];
    #pragma unroll
    for (int h = 0; h < 4; ++h) inv[h] = 1.f / sm[h];

    // gather: lanes 0-31 take even edges, lanes 32-63 odd edges; float4 (4 cols) per lane
    const int half = lane >> 5, l32 = lane & 31;
    const int coff = l32 * 4;
    float acc[4][4] = {};                 // [head][col]
    for (int i = 0; i < cnt; i += 2) {
        int ii = i + half;
        if (ii < cnt) {
            int sg = sh_src[wave][ii];
            float4 sv = *reinterpret_cast<const float4*>(&s[(size_t)sg * D + coff]);
            float4 alv = *reinterpret_cast<const float4*>(&sh_alpha[wave][ii][0]);
            float al[4] = {alv.x, alv.y, alv.z, alv.w};
            float cv[4] = {sv.x, sv.y, sv.z, sv.w};
            #pragma unroll
            for (int h = 0; h < 4; ++h)
                #pragma unroll
                for (int c = 0; c < 4; ++c) acc[h][c] += al[h] * cv[c];
        }
    }
    #pragma unroll
    for (int h = 0; h < 4; ++h)
        #pragma unroll
        for (int c = 0; c < 4; ++c) acc[h][c] += __shfl_xor(acc[h][c], 32);
    // A-fragment-packed write: z element (node n, col kg) -> 
    //   idx = (((n>>4)*16 + (kg>>5))*64 + ((kg&31)>>3)*16 + (n&15))*8 + (kg&7)
    // This lane owns heads {half*2, half*2+1}, cols coff..coff+3 (within one j-group).
    const int rt16 = (n >> 4) * 16, lrow = n & 15;
    #pragma unroll
    for (int hh = 0; hh < 2; ++hh) {
        int h = half * 2 + hh;
        ushort4 zh, zl;
        float v0 = acc[h][0] * inv[h], v1 = acc[h][1] * inv[h];
        float v2 = acc[h][2] * inv[h], v3 = acc[h][3] * inv[h];
        zh.x = f2bf(v0); zh.y = f2bf(v1); zh.z = f2bf(v2); zh.w = f2bf(v3);
        zl.x = f2bf(v0 - bf2f(zh.x)); zl.y = f2bf(v1 - bf2f(zh.y));
        zl.z = f2bf(v2 - bf2f(zh.z)); zl.w = f2bf(v3 - bf2f(zh.w));
        const int kstep = h * 4 + (l32 >> 3);
        const int slot  = (l32 >> 1) & 3;
        const int jo    = (l32 & 1) * 4;
        size_t idx = ((size_t)(rt16 + kstep) * 64 + slot * 16 + lrow) * 8 + jo;
        *reinterpret_cast<ushort4*>(&z_hi[idx]) = zh;
        *reinterpret_cast<ushort4*>(&z_lo[idx]) = zl;
    }
}

// ======== out[m,d] = z[m,:] . Pcat[d,:] + cvec[d]  (split-bf16 MFMA, frag-packed A&B) ==
// Grid: 512 blocks (one 16-row tile each) x 8 waves (one 16-col tile each).
// All loads are fully-coalesced 1KB frag streams; A-frags shared by the 8 waves (L1).
__global__ __launch_bounds__(512) void out_mfma(const unsigned short* __restrict__ z_hi,
                                                const unsigned short* __restrict__ z_lo,
                                                const unsigned short* __restrict__ p_hi,
                                                const unsigned short* __restrict__ p_lo,
                                                const float* __restrict__ cvec,
                                                float* __restrict__ out) {
    const int ct = threadIdx.x >> 6, lane = threadIdx.x & 63;
    const int rt = blockIdx.x;
    f32x4 acc = {0.f, 0.f, 0.f, 0.f};
    const unsigned short* za = z_hi + ((size_t)rt * 16 * 64 + lane) * 8;
    const unsigned short* zb = z_lo + ((size_t)rt * 16 * 64 + lane) * 8;
    const unsigned short* pb = p_hi + ((size_t)ct * 16 * 64 + lane) * 8;
    const unsigned short* pl = p_lo + ((size_t)ct * 16 * 64 + lane) * 8;
    #pragma unroll
    for (int ks = 0; ks < 16; ++ks) {
        s16x8 ah = *reinterpret_cast<const s16x8*>(za + ks * 512);
        s16x8 al = *reinterpret_cast<const s16x8*>(zb + ks * 512);
        s16x8 bh = *reinterpret_cast<const s16x8*>(pb + ks * 512);
        s16x8 bl = *reinterpret_cast<const s16x8*>(pl + ks * 512);
        acc = __builtin_amdgcn_mfma_f32_16x16x32_bf16(ah, bh, acc, 0, 0, 0);
        acc = __builtin_amdgcn_mfma_f32_16x16x32_bf16(ah, bl, acc, 0, 0, 0);
        acc = __builtin_amdgcn_mfma_f32_16x16x32_bf16(al, bh, acc, 0, 0, 0);
    }
    // C/D layout: col = lane&15, row = (lane>>4)*4 + reg
    const int ocol = ct * 16 + (lane & 15);
    const int orow = rt * 16 + (lane >> 4) * 4;
    const float cb = cvec[ocol];
    #pragma unroll
    for (int r = 0; r < 4; ++r)
        out[(size_t)(orow + r) * D + ocol] = acc[r] + cb;
}

extern "C" void kernel_launch(void* const* d_in, const int* in_sizes, int n_in,
                              void* d_out, int out_size, void* d_ws, size_t ws_size,
                              hipStream_t stream) {
    const float* s       = (const float*)d_in[0];
    const int*   ei      = (const int*)d_in[1];
    const float* W       = (const float*)d_in[2];
    const float* att_src = (const float*)d_in[3];
    const float* att_dst = (const float*)d_in[4];
    const float* bias    = (const float*)d_in[5];
    const float* Wo      = (const float*)d_in[6];
    const float* bo      = (const float*)d_in[7];
    float* out = (float*)d_out;

    char* ws = (char*)d_ws;
    float* w_src = (float*)ws; ws += 512 * 4;
    float* w_dst = (float*)ws; ws += 512 * 4;
    float* a_src = (float*)ws; ws += (size_t)N * H * 4;
    float* a_dst = (float*)ws; ws += (size_t)N * H * 4;
    float* cvec  = (float*)ws; ws += 512;
    unsigned short* z_hi = (unsigned short*)ws; ws += (size_t)N * HC * 2;
    unsigned short* z_lo = (unsigned short*)ws; ws += (size_t)N * HC * 2;
    unsigned short* p_hi = (unsigned short*)ws; ws += (size_t)D * HC * 2;
    unsigned short* p_lo = (unsigned short*)ws; ws += (size_t)D * HC * 2;
    int* cursor = (int*)ws; ws += SEQ * 4;
    int* csr0   = (int*)ws; ws += (size_t)SEQ * SLOTS * 4;

    prep_all<<<394, 256, 0, stream>>>(W, att_src, att_dst, bias, Wo, bo,
                                      w_src, w_dst, p_hi, p_lo, cvec, cursor);
    att_fill<<<N / 4, 256, 0, stream>>>(s, w_src, w_dst, ei, a_src, a_dst, cursor, csr0);
    node_aggregate_z<<<N / 4, 256, 0, stream>>>(cursor, csr0, a_src, a_dst, s, z_hi, z_lo);
    out_mfma<<<N / 16, 512, 0, stream>>>(z_hi, z_lo, p_hi, p_lo, cvec, out);
}

// Round 7
// 59.722 us; speedup vs baseline: 1.0810x; 1.0810x over previous
//
#include <hip/hip_runtime.h>

// Problem constants (fixed by reference)
constexpr int BSZ = 4, SEQ = 2048, D = 128, H = 4, E = 65536;
constexpr int N  = BSZ * SEQ;   // 8192 nodes
constexpr int HC = H * D;       // 512
constexpr int SLOTS = 128;      // per-dst bucket capacity; in-deg ~ Binom(65536,1/2048), mean 32
constexpr int MAXE  = SLOTS + 4;

typedef __attribute__((ext_vector_type(8))) short s16x8;
typedef __attribute__((ext_vector_type(4))) float f32x4;

__device__ inline unsigned short f2bf(float v) {            // fp32 -> bf16 RNE
    unsigned u = __float_as_uint(v);
    return (unsigned short)((u + 0x7fffu + ((u >> 16) & 1u)) >> 16);
}
__device__ inline float bf2f(unsigned short h) { return __uint_as_float(((unsigned)h) << 16); }

// ================= prep_all: block-specialized =================
// b in [0,256)   : Pcat[d, h*128+k] = sum_c Wo[d,h*128+c] * W[h*128+c, k]
//                  written in MFMA B-fragment-packed order (split bf16)
// b in [256,384) : cvec[d] = sum_j bias[j]*Wo[d,j] + bo[d]
// b in [384,386) : w_src[h,d] = sum_c att_src[h,c]*W[h*128+c, d]  (and w_dst)
// b in [386,394) : zero cursor[0..2047]
__global__ __launch_bounds__(256) void prep_all(const float* __restrict__ W,
                                                const float* __restrict__ att_src,
                                                const float* __restrict__ att_dst,
                                                const float* __restrict__ bias,
                                                const float* __restrict__ Wo,
                                                const float* __restrict__ bo,
                                                float* __restrict__ w_src,
                                                float* __restrict__ w_dst,
                                                unsigned short* __restrict__ p_hi,
                                                unsigned short* __restrict__ p_lo,
                                                float* __restrict__ cvec,
                                                int* __restrict__ cursor) {
    __shared__ float part[4];
    const int b = blockIdx.x, tid = threadIdx.x;
    if (b < 256) {                      // --- prep_P (fragment-packed) ---
        int h = b & 3;
        int d = (b >> 2) * 2 + (tid >> 7);
        int k = tid & 127;
        float acc = 0.f;
        for (int c = 0; c < D; ++c)
            acc += Wo[d * HC + h * D + c] * W[(h * D + c) * D + k];
        unsigned short hi = f2bf(acc);
        // B-fragment packing for mfma_f32_16x16x32_bf16:
        // element (col=d, kglobal=h*128+k) lives at lane=(kin>>3)*16+(d&15), j=kin&7
        int ct = d >> 4, lrow = d & 15;
        int kg = h * D + k, kstep = kg >> 5, kin = kg & 31;
        size_t idx = ((size_t)(ct * 16 + kstep) * 64 + (kin >> 3) * 16 + lrow) * 8 + (kin & 7);
        p_hi[idx] = hi;
        p_lo[idx] = f2bf(acc - bf2f(hi));
    } else if (b < 384) {               // --- prep_c ---
        int d = b - 256;
        float a = bias[tid] * Wo[d * HC + tid] + bias[tid + 256] * Wo[d * HC + tid + 256];
        #pragma unroll
        for (int off = 32; off; off >>= 1) a += __shfl_xor(a, off);
        if ((tid & 63) == 0) part[tid >> 6] = a;
        __syncthreads();
        if (tid == 0) cvec[d] = part[0] + part[1] + part[2] + part[3] + bo[d];
    } else if (b < 386) {               // --- prep_w ---
        int t = (b - 384) * 256 + tid;  // 0..511
        int h = t >> 7, dd = t & 127;
        float ws = 0.f, wd = 0.f;
        for (int c = 0; c < D; ++c) {
            float wv = W[(h * D + c) * D + dd];
            ws += att_src[h * D + c] * wv;
            wd += att_dst[h * D + c] * wv;
        }
        w_src[t] = ws;
        w_dst[t] = wd;
    } else {                            // --- zero cursor ---
        int idx = (b - 386) * 256 + tid;
        if (idx < SEQ) cursor[idx] = 0;
    }
}

// ======== att_fill: a_src/a_dst per node; first 256 blocks also bucket the edges ========
__global__ __launch_bounds__(256) void att_fill(const float* __restrict__ s,
                                                const float* __restrict__ w_src,
                                                const float* __restrict__ w_dst,
                                                const int* __restrict__ ei,
                                                float* __restrict__ a_src,
                                                float* __restrict__ a_dst,
                                                int* __restrict__ cursor,
                                                int* __restrict__ csr0) {
    const int bid = blockIdx.x, tid = threadIdx.x;
    if (bid < 256) {                    // bucket-fill: one edge per thread
        int e = bid * 256 + tid;
        int src = ei[e], dst = ei[E + e];
        int slot = atomicAdd(&cursor[dst], 1);
        if (slot < SLOTS) csr0[dst * SLOTS + slot] = src;
    }
    const int wave = tid >> 6, lane = tid & 63;
    const int n = bid * 4 + wave;
    float s0 = s[n * D + lane];
    float s1 = s[n * D + 64 + lane];
    #pragma unroll
    for (int h = 0; h < H; ++h) {
        float ps = s0 * w_src[h * D + lane] + s1 * w_src[h * D + 64 + lane];
        float pd = s0 * w_dst[h * D + lane] + s1 * w_dst[h * D + 64 + lane];
        #pragma unroll
        for (int off = 32; off; off >>= 1) {
            ps += __shfl_xor(ps, off);
            pd += __shfl_xor(pd, off);
        }
        if (lane == 0) {
            a_src[n * H + h] = ps;
            a_dst[n * H + h] = pd;
        }
    }
}

// ======== fused: per-dst softmax + gather -> z frags in LDS -> MFMA out ========
// Block = 512 threads (8 waves) handles 16 dst nodes (one 16-row out tile).
// Phase 1: wave w processes nodes w*2 and w*2+1 (softmax over in-edges, weighted
//          gather of s rows), writes split-bf16 z into LDS in A-fragment order.
// Phase 2 (after one barrier): wave w computes out 16-col tile ct=w via MFMA,
//          A-frags from LDS, B-frags (Pcat) from coalesced global streams.
__global__ __launch_bounds__(512, 4) void agg_out(const int* __restrict__ cursor,
                                                  const int* __restrict__ csr0,
                                                  const float* __restrict__ a_src,
                                                  const float* __restrict__ a_dst,
                                                  const float* __restrict__ s,
                                                  const unsigned short* __restrict__ p_hi,
                                                  const unsigned short* __restrict__ p_lo,
                                                  const float* __restrict__ cvec,
                                                  float* __restrict__ out) {
    __shared__ short    zf[2][16][512];            // [hi/lo][kstep][lane*8+j]  (32 KB)
    __shared__ float    sh_alpha[8][MAXE][4];
    __shared__ int      sh_src[8][MAXE];
    const int w = threadIdx.x >> 6, lane = threadIdx.x & 63;
    const int half = lane >> 5, l32 = lane & 31;

    for (int rep = 0; rep < 2; ++rep) {
        const int r = w * 2 + rep;                 // row in tile (== n & 15)
        const int n = blockIdx.x * 16 + r;
        const int b = n >> 11, dloc = n & 2047;
        int deg = cursor[dloc];
        deg = (deg < SLOTS) ? deg : SLOTS;
        const int beg = dloc * SLOTS;
        const int cnt = deg + 1;                   // + self loop
        float4 adv = *reinterpret_cast<const float4*>(&a_dst[n * H]);
        float ad[4] = {adv.x, adv.y, adv.z, adv.w};
        float mx[4] = {-1e30f, -1e30f, -1e30f, -1e30f};
        for (int i = lane; i < cnt; i += 64) {
            int sg = (i < deg) ? (csr0[beg + i] + (b << 11)) : n;
            sh_src[w][i] = sg;
            float4 asv = *reinterpret_cast<const float4*>(&a_src[sg * H]);
            float lg[4] = {asv.x, asv.y, asv.z, asv.w};
            #pragma unroll
            for (int h = 0; h < 4; ++h) {
                float l = lg[h] + ad[h];
                l = (l > 0.f) ? l : 0.2f * l;
                sh_alpha[w][i][h] = l;
                mx[h] = fmaxf(mx[h], l);
            }
        }
        #pragma unroll
        for (int h = 0; h < 4; ++h)
            #pragma unroll
            for (int off = 32; off; off >>= 1) mx[h] = fmaxf(mx[h], __shfl_xor(mx[h], off));
        float sm[4] = {0.f, 0.f, 0.f, 0.f};
        for (int i = lane; i < cnt; i += 64) {
            #pragma unroll
            for (int h = 0; h < 4; ++h) {
                float ev = expf(sh_alpha[w][i][h] - mx[h]);
                sh_alpha[w][i][h] = ev;
                sm[h] += ev;
            }
        }
        #pragma unroll
        for (int h = 0; h < 4; ++h)
            #pragma unroll
            for (int off = 32; off; off >>= 1) sm[h] += __shfl_xor(sm[h], off);
        float inv[4];
        #pragma unroll
        for (int h = 0; h < 4; ++h) inv[h] = 1.f / sm[h];

        // gather: lanes 0-31 even edges, lanes 32-63 odd edges; float4 per lane
        const int coff = l32 * 4;
        float acc[4][4] = {};                      // [head][col]
        for (int i = 0; i < cnt; i += 2) {
            int ii = i + half;
            if (ii < cnt) {
                int sg = sh_src[w][ii];
                float4 sv = *reinterpret_cast<const float4*>(&s[(size_t)sg * D + coff]);
                float4 alv = *reinterpret_cast<const float4*>(&sh_alpha[w][ii][0]);
                float al[4] = {alv.x, alv.y, alv.z, alv.w};
                float cv[4] = {sv.x, sv.y, sv.z, sv.w};
                #pragma unroll
                for (int h = 0; h < 4; ++h)
                    #pragma unroll
                    for (int c = 0; c < 4; ++c) acc[h][c] += al[h] * cv[c];
            }
        }
        #pragma unroll
        for (int h = 0; h < 4; ++h)
            #pragma unroll
            for (int c = 0; c < 4; ++c) acc[h][c] += __shfl_xor(acc[h][c], 32);
        // write z fragments (split bf16) into LDS, A-frag-packed:
        // this lane owns heads {half*2, half*2+1}, cols coff..coff+3
        #pragma unroll
        for (int hh = 0; hh < 2; ++hh) {
            int h = half * 2 + hh;
            ushort4 zh, zl;
            float v0 = acc[h][0] * inv[h], v1 = acc[h][1] * inv[h];
            float v2 = acc[h][2] * inv[h], v3 = acc[h][3] * inv[h];
            zh.x = f2bf(v0); zh.y = f2bf(v1); zh.z = f2bf(v2); zh.w = f2bf(v3);
            zl.x = f2bf(v0 - bf2f(zh.x)); zl.y = f2bf(v1 - bf2f(zh.y));
            zl.z = f2bf(v2 - bf2f(zh.z)); zl.w = f2bf(v3 - bf2f(zh.w));
            const int kstep = h * 4 + (l32 >> 3);
            const int slot  = (l32 >> 1) & 3;
            const int jo    = (l32 & 1) * 4;
            const int off   = (slot * 16 + r) * 8 + jo;
            *reinterpret_cast<ushort4*>(&zf[0][kstep][off]) = zh;
            *reinterpret_cast<ushort4*>(&zf[1][kstep][off]) = zl;
        }
    }
    __syncthreads();

    // ---- MFMA phase: wave w -> 16-col tile ct = w ----
    f32x4 acc = {0.f, 0.f, 0.f, 0.f};
    const unsigned short* pb = p_hi + ((size_t)w * 16 * 64 + lane) * 8;
    const unsigned short* pl = p_lo + ((size_t)w * 16 * 64 + lane) * 8;
    #pragma unroll
    for (int ks = 0; ks < 16; ++ks) {
        s16x8 ah = *reinterpret_cast<const s16x8*>(&zf[0][ks][lane * 8]);
        s16x8 al = *reinterpret_cast<const s16x8*>(&zf[1][ks][lane * 8]);
        s16x8 bh = *reinterpret_cast<const s16x8*>(pb + ks * 512);
        s16x8 bl = *reinterpret_cast<const s16x8*>(pl + ks * 512);
        acc = __builtin_amdgcn_mfma_f32_16x16x32_bf16(ah, bh, acc, 0, 0, 0);
        acc = __builtin_amdgcn_mfma_f32_16x16x32_bf16(ah, bl, acc, 0, 0, 0);
        acc = __builtin_amdgcn_mfma_f32_16x16x32_bf16(al, bh, acc, 0, 0, 0);
    }
    // C/D layout: col = lane&15, row = (lane>>4)*4 + reg
    const int ocol = w * 16 + (lane & 15);
    const int orow = blockIdx.x * 16 + (lane >> 4) * 4;
    const float cb = cvec[ocol];
    #pragma unroll
    for (int r2 = 0; r2 < 4; ++r2)
        out[(size_t)(orow + r2) * D + ocol] = acc[r2] + cb;
}

extern "C" void kernel_launch(void* const* d_in, const int* in_sizes, int n_in,
                              void* d_out, int out_size, void* d_ws, size_t ws_size,
                              hipStream_t stream) {
    const float* s       = (const float*)d_in[0];
    const int*   ei      = (const int*)d_in[1];
    const float* W       = (const float*)d_in[2];
    const float* att_src = (const float*)d_in[3];
    const float* att_dst = (const float*)d_in[4];
    const float* bias    = (const float*)d_in[5];
    const float* Wo      = (const float*)d_in[6];
    const float* bo      = (const float*)d_in[7];
    float* out = (float*)d_out;

    char* ws = (char*)d_ws;
    float* w_src = (float*)ws; ws += 512 * 4;
    float* w_dst = (float*)ws; ws += 512 * 4;
    float* a_src = (float*)ws; ws += (size_t)N * H * 4;
    float* a_dst = (float*)ws; ws += (size_t)N * H * 4;
    float* cvec  = (float*)ws; ws += 512;
    unsigned short* p_hi = (unsigned short*)ws; ws += (size_t)D * HC * 2;
    unsigned short* p_lo = (unsigned short*)ws; ws += (size_t)D * HC * 2;
    int* cursor = (int*)ws; ws += SEQ * 4;
    int* csr0   = (int*)ws; ws += (size_t)SEQ * SLOTS * 4;

    prep_all<<<394, 256, 0, stream>>>(W, att_src, att_dst, bias, Wo, bo,
                                      w_src, w_dst, p_hi, p_lo, cvec, cursor);
    att_fill<<<N / 4, 256, 0, stream>>>(s, w_src, w_dst, ei, a_src, a_dst, cursor, csr0);
    agg_out<<<N / 16, 512, 0, stream>>>(cursor, csr0, a_src, a_dst, s,
                                        p_hi, p_lo, cvec, out);
}

// Round 8
// 49.760 us; speedup vs baseline: 1.2975x; 1.2002x over previous
//
#include <hip/hip_runtime.h>

// Problem constants (fixed by reference)
constexpr int BSZ = 4, SEQ = 2048, D = 128, H = 4, E = 65536;
constexpr int N  = BSZ * SEQ;   // 8192 nodes
constexpr int HC = H * D;       // 512
constexpr int SLOTS = 128;      // per-dst bucket capacity; in-deg ~ Binom(65536,1/2048), mean 32
constexpr int MAXE  = SLOTS + 4;

typedef __attribute__((ext_vector_type(8))) short s16x8;
typedef __attribute__((ext_vector_type(4))) float f32x4;

__device__ inline unsigned short f2bf(float v) {            // fp32 -> bf16 RNE
    unsigned u = __float_as_uint(v);
    return (unsigned short)((u + 0x7fffu + ((u >> 16) & 1u)) >> 16);
}
__device__ inline float bf2f(unsigned short h) { return __uint_as_float(((unsigned)h) << 16); }

// ================= prep_all: block-specialized =================
// b in [0,256)   : Pcat[d, h*128+k] = sum_c Wo[d,h*128+c] * W[h*128+c, k]
//                  written in MFMA B-fragment-packed order (split bf16)
// b in [256,384) : cvec[d] = sum_j bias[j]*Wo[d,j] + bo[d]
// b in [384,386) : w_src[h,d] = sum_c att_src[h,c]*W[h*128+c, d]  (and w_dst)
// b in [386,394) : zero cursor[0..2047]
__global__ __launch_bounds__(256) void prep_all(const float* __restrict__ W,
                                                const float* __restrict__ att_src,
                                                const float* __restrict__ att_dst,
                                                const float* __restrict__ bias,
                                                const float* __restrict__ Wo,
                                                const float* __restrict__ bo,
                                                float* __restrict__ w_src,
                                                float* __restrict__ w_dst,
                                                unsigned short* __restrict__ p_hi,
                                                unsigned short* __restrict__ p_lo,
                                                float* __restrict__ cvec,
                                                int* __restrict__ cursor) {
    __shared__ float part[4];
    const int b = blockIdx.x, tid = threadIdx.x;
    if (b < 256) {                      // --- prep_P (fragment-packed) ---
        int h = b & 3;
        int d = (b >> 2) * 2 + (tid >> 7);
        int k = tid & 127;
        float acc = 0.f;
        for (int c = 0; c < D; ++c)
            acc += Wo[d * HC + h * D + c] * W[(h * D + c) * D + k];
        unsigned short hi = f2bf(acc);
        // B-fragment packing for mfma_f32_16x16x32_bf16:
        // element (col=d, kglobal=h*128+k) lives at lane=(kin>>3)*16+(d&15), j=kin&7
        int ct = d >> 4, lrow = d & 15;
        int kg = h * D + k, kstep = kg >> 5, kin = kg & 31;
        size_t idx = ((size_t)(ct * 16 + kstep) * 64 + (kin >> 3) * 16 + lrow) * 8 + (kin & 7);
        p_hi[idx] = hi;
        p_lo[idx] = f2bf(acc - bf2f(hi));
    } else if (b < 384) {               // --- prep_c ---
        int d = b - 256;
        float a = bias[tid] * Wo[d * HC + tid] + bias[tid + 256] * Wo[d * HC + tid + 256];
        #pragma unroll
        for (int off = 32; off; off >>= 1) a += __shfl_xor(a, off);
        if ((tid & 63) == 0) part[tid >> 6] = a;
        __syncthreads();
        if (tid == 0) cvec[d] = part[0] + part[1] + part[2] + part[3] + bo[d];
    } else if (b < 386) {               // --- prep_w ---
        int t = (b - 384) * 256 + tid;  // 0..511
        int h = t >> 7, dd = t & 127;
        float ws = 0.f, wd = 0.f;
        for (int c = 0; c < D; ++c) {
            float wv = W[(h * D + c) * D + dd];
            ws += att_src[h * D + c] * wv;
            wd += att_dst[h * D + c] * wv;
        }
        w_src[t] = ws;
        w_dst[t] = wd;
    } else {                            // --- zero cursor ---
        int idx = (b - 386) * 256 + tid;
        if (idx < SEQ) cursor[idx] = 0;
    }
}

// ======== att_fill: a_src/a_dst per node; first 256 blocks also bucket the edges ========
__global__ __launch_bounds__(256) void att_fill(const float* __restrict__ s,
                                                const float* __restrict__ w_src,
                                                const float* __restrict__ w_dst,
                                                const int* __restrict__ ei,
                                                float* __restrict__ a_src,
                                                float* __restrict__ a_dst,
                                                int* __restrict__ cursor,
                                                int* __restrict__ csr0) {
    const int bid = blockIdx.x, tid = threadIdx.x;
    if (bid < 256) {                    // bucket-fill: one edge per thread
        int e = bid * 256 + tid;
        int src = ei[e], dst = ei[E + e];
        int slot = atomicAdd(&cursor[dst], 1);
        if (slot < SLOTS) csr0[dst * SLOTS + slot] = src;
    }
    const int wave = tid >> 6, lane = tid & 63;
    const int n = bid * 4 + wave;
    float s0 = s[n * D + lane];
    float s1 = s[n * D + 64 + lane];
    #pragma unroll
    for (int h = 0; h < H; ++h) {
        float ps = s0 * w_src[h * D + lane] + s1 * w_src[h * D + 64 + lane];
        float pd = s0 * w_dst[h * D + lane] + s1 * w_dst[h * D + 64 + lane];
        #pragma unroll
        for (int off = 32; off; off >>= 1) {
            ps += __shfl_xor(ps, off);
            pd += __shfl_xor(pd, off);
        }
        if (lane == 0) {
            a_src[n * H + h] = ps;
            a_dst[n * H + h] = pd;
        }
    }
}

// ======== fused: per-dst softmax + gather -> z frags in LDS -> MFMA out ========
// Block = 512 threads (8 waves) handles 16 dst nodes (one 16-row out tile).
// XCD-aware swizzle: batch b's blocks land on XCDs {2b,2b+1} (blockIdx%8 ~ XCD),
// so each XCD's gather working set is one 1MB batch slice of s (+P/csr) -> L2-resident.
__global__ __launch_bounds__(512, 4) void agg_out(const int* __restrict__ cursor,
                                                  const int* __restrict__ csr0,
                                                  const float* __restrict__ a_src,
                                                  const float* __restrict__ a_dst,
                                                  const float* __restrict__ s,
                                                  const unsigned short* __restrict__ p_hi,
                                                  const unsigned short* __restrict__ p_lo,
                                                  const float* __restrict__ cvec,
                                                  float* __restrict__ out) {
    __shared__ short    zf[2][16][512];            // [hi/lo][kstep][lane*8+j]  (32 KB)
    __shared__ float    sh_alpha[8][MAXE][4];
    __shared__ int      sh_src[8][MAXE];
    // ---- XCD swizzle: bid = ((i>>1)<<3) | (b<<1) | (i&1)  (bijective) ----
    const int bid = blockIdx.x;
    const int batch = (bid & 7) >> 1;              // 0..3
    const int itile = ((bid >> 3) << 1) | (bid & 1); // 0..127 within batch
    const int tile  = batch * 128 + itile;         // original 16-row tile id
    const int w = threadIdx.x >> 6, lane = threadIdx.x & 63;
    const int half = lane >> 5, l32 = lane & 31;

    for (int rep = 0; rep < 2; ++rep) {
        const int r = w * 2 + rep;                 // row in tile (== n & 15)
        const int n = tile * 16 + r;
        const int dloc = n & 2047;
        int deg = cursor[dloc];
        deg = (deg < SLOTS) ? deg : SLOTS;
        const int beg = dloc * SLOTS;
        const int cnt = deg + 1;                   // + self loop
        float4 adv = *reinterpret_cast<const float4*>(&a_dst[n * H]);
        float ad[4] = {adv.x, adv.y, adv.z, adv.w};
        float mx[4] = {-1e30f, -1e30f, -1e30f, -1e30f};
        for (int i = lane; i < cnt; i += 64) {
            int sg = (i < deg) ? (csr0[beg + i] + (batch << 11)) : n;
            sh_src[w][i] = sg;
            float4 asv = *reinterpret_cast<const float4*>(&a_src[sg * H]);
            float lg[4] = {asv.x, asv.y, asv.z, asv.w};
            #pragma unroll
            for (int h = 0; h < 4; ++h) {
                float l = lg[h] + ad[h];
                l = (l > 0.f) ? l : 0.2f * l;
                sh_alpha[w][i][h] = l;
                mx[h] = fmaxf(mx[h], l);
            }
        }
        #pragma unroll
        for (int h = 0; h < 4; ++h)
            #pragma unroll
            for (int off = 32; off; off >>= 1) mx[h] = fmaxf(mx[h], __shfl_xor(mx[h], off));
        float sm[4] = {0.f, 0.f, 0.f, 0.f};
        for (int i = lane; i < cnt; i += 64) {
            #pragma unroll
            for (int h = 0; h < 4; ++h) {
                float ev = __expf(sh_alpha[w][i][h] - mx[h]);
                sh_alpha[w][i][h] = ev;
                sm[h] += ev;
            }
        }
        #pragma unroll
        for (int h = 0; h < 4; ++h)
            #pragma unroll
            for (int off = 32; off; off >>= 1) sm[h] += __shfl_xor(sm[h], off);
        float inv[4];
        #pragma unroll
        for (int h = 0; h < 4; ++h) inv[h] = 1.f / sm[h];

        // gather: lanes 0-31 even edges, lanes 32-63 odd edges; float4 per lane.
        // 2x unrolled: two independent row-loads in flight per lane.
        const int coff = l32 * 4;
        float acc[4][4] = {};                      // [head][col]
        int i = 0;
        for (; i + 4 <= cnt; i += 4) {
            int iA = i + half, iB = i + 2 + half;
            int sgA = sh_src[w][iA], sgB = sh_src[w][iB];
            float4 svA = *reinterpret_cast<const float4*>(&s[(size_t)sgA * D + coff]);
            float4 svB = *reinterpret_cast<const float4*>(&s[(size_t)sgB * D + coff]);
            float4 alA = *reinterpret_cast<const float4*>(&sh_alpha[w][iA][0]);
            float4 alB = *reinterpret_cast<const float4*>(&sh_alpha[w][iB][0]);
            float aA[4] = {alA.x, alA.y, alA.z, alA.w};
            float aB[4] = {alB.x, alB.y, alB.z, alB.w};
            float cA[4] = {svA.x, svA.y, svA.z, svA.w};
            float cB[4] = {svB.x, svB.y, svB.z, svB.w};
            #pragma unroll
            for (int h = 0; h < 4; ++h)
                #pragma unroll
                for (int c = 0; c < 4; ++c)
                    acc[h][c] += aA[h] * cA[c] + aB[h] * cB[c];
        }
        for (; i < cnt; i += 2) {
            int ii = i + half;
            if (ii < cnt) {
                int sg = sh_src[w][ii];
                float4 sv = *reinterpret_cast<const float4*>(&s[(size_t)sg * D + coff]);
                float4 alv = *reinterpret_cast<const float4*>(&sh_alpha[w][ii][0]);
                float al[4] = {alv.x, alv.y, alv.z, alv.w};
                float cv[4] = {sv.x, sv.y, sv.z, sv.w};
                #pragma unroll
                for (int h = 0; h < 4; ++h)
                    #pragma unroll
                    for (int c = 0; c < 4; ++c) acc[h][c] += al[h] * cv[c];
            }
        }
        #pragma unroll
        for (int h = 0; h < 4; ++h)
            #pragma unroll
            for (int c = 0; c < 4; ++c) acc[h][c] += __shfl_xor(acc[h][c], 32);
        // write z fragments (split bf16) into LDS, A-frag-packed:
        // this lane owns heads {half*2, half*2+1}, cols coff..coff+3
        #pragma unroll
        for (int hh = 0; hh < 2; ++hh) {
            int h = half * 2 + hh;
            ushort4 zh, zl;
            float v0 = acc[h][0] * inv[h], v1 = acc[h][1] * inv[h];
            float v2 = acc[h][2] * inv[h], v3 = acc[h][3] * inv[h];
            zh.x = f2bf(v0); zh.y = f2bf(v1); zh.z = f2bf(v2); zh.w = f2bf(v3);
            zl.x = f2bf(v0 - bf2f(zh.x)); zl.y = f2bf(v1 - bf2f(zh.y));
            zl.z = f2bf(v2 - bf2f(zh.z)); zl.w = f2bf(v3 - bf2f(zh.w));
            const int kstep = h * 4 + (l32 >> 3);
            const int slot  = (l32 >> 1) & 3;
            const int jo    = (l32 & 1) * 4;
            const int off   = (slot * 16 + r) * 8 + jo;
            *reinterpret_cast<ushort4*>(&zf[0][kstep][off]) = zh;
            *reinterpret_cast<ushort4*>(&zf[1][kstep][off]) = zl;
        }
    }
    __syncthreads();

    // ---- MFMA phase: wave w -> 16-col tile ct = w ----
    f32x4 acc = {0.f, 0.f, 0.f, 0.f};
    const unsigned short* pb = p_hi + ((size_t)w * 16 * 64 + lane) * 8;
    const unsigned short* pl = p_lo + ((size_t)w * 16 * 64 + lane) * 8;
    #pragma unroll
    for (int ks = 0; ks < 16; ++ks) {
        s16x8 ah = *reinterpret_cast<const s16x8*>(&zf[0][ks][lane * 8]);
        s16x8 al = *reinterpret_cast<const s16x8*>(&zf[1][ks][lane * 8]);
        s16x8 bh = *reinterpret_cast<const s16x8*>(pb + ks * 512);
        s16x8 bl = *reinterpret_cast<const s16x8*>(pl + ks * 512);
        acc = __builtin_amdgcn_mfma_f32_16x16x32_bf16(ah, bh, acc, 0, 0, 0);
        acc = __builtin_amdgcn_mfma_f32_16x16x32_bf16(ah, bl, acc, 0, 0, 0);
        acc = __builtin_amdgcn_mfma_f32_16x16x32_bf16(al, bh, acc, 0, 0, 0);
    }
    // C/D layout: col = lane&15, row = (lane>>4)*4 + reg
    const int ocol = w * 16 + (lane & 15);
    const int orow = tile * 16 + (lane >> 4) * 4;
    const float cb = cvec[ocol];
    #pragma unroll
    for (int r2 = 0; r2 < 4; ++r2)
        out[(size_t)(orow + r2) * D + ocol] = acc[r2] + cb;
}

extern "C" void kernel_launch(void* const* d_in, const int* in_sizes, int n_in,
                              void* d_out, int out_size, void* d_ws, size_t ws_size,
                              hipStream_t stream) {
    const float* s       = (const float*)d_in[0];
    const int*   ei      = (const int*)d_in[1];
    const float* W       = (const float*)d_in[2];
    const float* att_src = (const float*)d_in[3];
    const float* att_dst = (const float*)d_in[4];
    const float* bias    = (const float*)d_in[5];
    const float* Wo      = (const float*)d_in[6];
    const float* bo      = (const float*)d_in[7];
    float* out = (float*)d_out;

    char* ws = (char*)d_ws;
    float* w_src = (float*)ws; ws += 512 * 4;
    float* w_dst = (float*)ws; ws += 512 * 4;
    float* a_src = (float*)ws; ws += (size_t)N * H * 4;
    float* a_dst = (float*)ws; ws += (size_t)N * H * 4;
    float* cvec  = (float*)ws; ws += 512;
    unsigned short* p_hi = (unsigned short*)ws; ws += (size_t)D * HC * 2;
    unsigned short* p_lo = (unsigned short*)ws; ws += (size_t)D * HC * 2;
    int* cursor = (int*)ws; ws += SEQ * 4;
    int* csr0   = (int*)ws; ws += (size_t)SEQ * SLOTS * 4;

    prep_all<<<394, 256, 0, stream>>>(W, att_src, att_dst, bias, Wo, bo,
                                      w_src, w_dst, p_hi, p_lo, cvec, cursor);
    att_fill<<<N / 4, 256, 0, stream>>>(s, w_src, w_dst, ei, a_src, a_dst, cursor, csr0);
    agg_out<<<N / 16, 512, 0, stream>>>(cursor, csr0, a_src, a_dst, s,
                                        p_hi, p_lo, cvec, out);
}

// Round 9
// 47.310 us; speedup vs baseline: 1.3646x; 1.0518x over previous
//
#include <hip/hip_runtime.h>

// Problem constants (fixed by reference)
constexpr int BSZ = 4, SEQ = 2048, D = 128, H = 4, E = 65536;
constexpr int N  = BSZ * SEQ;   // 8192 nodes
constexpr int HC = H * D;       // 512
constexpr int SLOTS = 128;      // per-dst bucket capacity; in-deg ~ Binom(65536,1/2048), mean 32
constexpr int MAXE  = SLOTS + 4;

typedef __attribute__((ext_vector_type(8))) short s16x8;
typedef __attribute__((ext_vector_type(4))) float f32x4;

__device__ inline unsigned short f2bf(float v) {            // fp32 -> bf16 RNE
    unsigned u = __float_as_uint(v);
    return (unsigned short)((u + 0x7fffu + ((u >> 16) & 1u)) >> 16);
}
__device__ inline float bf2f(unsigned short h) { return __uint_as_float(((unsigned)h) << 16); }

// ================= prep_all: block-specialized =================
__global__ __launch_bounds__(256) void prep_all(const float* __restrict__ W,
                                                const float* __restrict__ att_src,
                                                const float* __restrict__ att_dst,
                                                const float* __restrict__ bias,
                                                const float* __restrict__ Wo,
                                                const float* __restrict__ bo,
                                                float* __restrict__ w_src,
                                                float* __restrict__ w_dst,
                                                unsigned short* __restrict__ p_hi,
                                                unsigned short* __restrict__ p_lo,
                                                float* __restrict__ cvec,
                                                int* __restrict__ cursor) {
    __shared__ float part[4];
    const int b = blockIdx.x, tid = threadIdx.x;
    if (b < 256) {                      // --- prep_P (fragment-packed) ---
        int h = b & 3;
        int d = (b >> 2) * 2 + (tid >> 7);
        int k = tid & 127;
        float acc = 0.f;
        for (int c = 0; c < D; ++c)
            acc += Wo[d * HC + h * D + c] * W[(h * D + c) * D + k];
        unsigned short hi = f2bf(acc);
        // B-fragment packing for mfma_f32_16x16x32_bf16:
        // element (col=d, kglobal=h*128+k) lives at lane=(kin>>3)*16+(d&15), j=kin&7
        int ct = d >> 4, lrow = d & 15;
        int kg = h * D + k, kstep = kg >> 5, kin = kg & 31;
        size_t idx = ((size_t)(ct * 16 + kstep) * 64 + (kin >> 3) * 16 + lrow) * 8 + (kin & 7);
        p_hi[idx] = hi;
        p_lo[idx] = f2bf(acc - bf2f(hi));
    } else if (b < 384) {               // --- prep_c ---
        int d = b - 256;
        float a = bias[tid] * Wo[d * HC + tid] + bias[tid + 256] * Wo[d * HC + tid + 256];
        #pragma unroll
        for (int off = 32; off; off >>= 1) a += __shfl_xor(a, off);
        if ((tid & 63) == 0) part[tid >> 6] = a;
        __syncthreads();
        if (tid == 0) cvec[d] = part[0] + part[1] + part[2] + part[3] + bo[d];
    } else if (b < 386) {               // --- prep_w ---
        int t = (b - 384) * 256 + tid;  // 0..511
        int h = t >> 7, dd = t & 127;
        float ws = 0.f, wd = 0.f;
        for (int c = 0; c < D; ++c) {
            float wv = W[(h * D + c) * D + dd];
            ws += att_src[h * D + c] * wv;
            wd += att_dst[h * D + c] * wv;
        }
        w_src[t] = ws;
        w_dst[t] = wd;
    } else {                            // --- zero cursor ---
        int idx = (b - 386) * 256 + tid;
        if (idx < SEQ) cursor[idx] = 0;
    }
}

// ======== att_fill: a_src/a_dst per node; first 256 blocks also bucket the edges ========
__global__ __launch_bounds__(256) void att_fill(const float* __restrict__ s,
                                                const float* __restrict__ w_src,
                                                const float* __restrict__ w_dst,
                                                const int* __restrict__ ei,
                                                float* __restrict__ a_src,
                                                float* __restrict__ a_dst,
                                                int* __restrict__ cursor,
                                                int* __restrict__ csr0) {
    const int bid = blockIdx.x, tid = threadIdx.x;
    if (bid < 256) {                    // bucket-fill: one edge per thread
        int e = bid * 256 + tid;
        int src = ei[e], dst = ei[E + e];
        int slot = atomicAdd(&cursor[dst], 1);
        if (slot < SLOTS) csr0[dst * SLOTS + slot] = src;
    }
    const int wave = tid >> 6, lane = tid & 63;
    const int n = bid * 4 + wave;
    float s0 = s[n * D + lane];
    float s1 = s[n * D + 64 + lane];
    #pragma unroll
    for (int h = 0; h < H; ++h) {
        float ps = s0 * w_src[h * D + lane] + s1 * w_src[h * D + 64 + lane];
        float pd = s0 * w_dst[h * D + lane] + s1 * w_dst[h * D + 64 + lane];
        #pragma unroll
        for (int off = 32; off; off >>= 1) {
            ps += __shfl_xor(ps, off);
            pd += __shfl_xor(pd, off);
        }
        if (lane == 0) {
            a_src[n * H + h] = ps;
            a_dst[n * H + h] = pd;
        }
    }
}

// ======== fused: per-dst softmax + gather -> z frags in LDS -> MFMA out ========
// Block = 512 threads (8 waves) handles 16 dst nodes (one 16-row out tile).
// XCD-aware swizzle: batch b's blocks land on XCDs {2b,2b+1} (blockIdx%8 ~ XCD),
// so each XCD's gather working set is one 1MB batch slice of s (+P/csr) -> L2-resident.
__global__ __launch_bounds__(512, 4) void agg_out(const int* __restrict__ cursor,
                                                  const int* __restrict__ csr0,
                                                  const float* __restrict__ a_src,
                                                  const float* __restrict__ a_dst,
                                                  const float* __restrict__ s,
                                                  const unsigned short* __restrict__ p_hi,
                                                  const unsigned short* __restrict__ p_lo,
                                                  const float* __restrict__ cvec,
                                                  float* __restrict__ out) {
    __shared__ short    zf[2][16][512];            // [hi/lo][kstep][lane*8+j]  (32 KB)
    __shared__ float    sh_alpha[8][MAXE][4];
    __shared__ int      sh_src[8][MAXE];
    // ---- XCD swizzle: bid = ((i>>1)<<3) | (b<<1) | (i&1)  (bijective) ----
    const int bid = blockIdx.x;
    const int batch = (bid & 7) >> 1;              // 0..3
    const int itile = ((bid >> 3) << 1) | (bid & 1); // 0..127 within batch
    const int tile  = batch * 128 + itile;         // original 16-row tile id
    const int w = threadIdx.x >> 6, lane = threadIdx.x & 63;
    const int half = lane >> 5, l32 = lane & 31;

    for (int rep = 0; rep < 2; ++rep) {
        const int r = w * 2 + rep;                 // row in tile (== n & 15)
        const int n = tile * 16 + r;
        const int dloc = n & 2047;
        int deg = cursor[dloc];
        deg = (deg < SLOTS) ? deg : SLOTS;
        const int beg = dloc * SLOTS;
        const int cnt = deg + 1;                   // + self loop
        float4 adv = *reinterpret_cast<const float4*>(&a_dst[n * H]);
        float ad[4] = {adv.x, adv.y, adv.z, adv.w};
        float mx[4] = {-1e30f, -1e30f, -1e30f, -1e30f};
        for (int i = lane; i < cnt; i += 64) {
            int sg = (i < deg) ? (csr0[beg + i] + (batch << 11)) : n;
            sh_src[w][i] = sg;
            float4 asv = *reinterpret_cast<const float4*>(&a_src[sg * H]);
            float lg[4] = {asv.x, asv.y, asv.z, asv.w};
            #pragma unroll
            for (int h = 0; h < 4; ++h) {
                float l = lg[h] + ad[h];
                l = (l > 0.f) ? l : 0.2f * l;
                sh_alpha[w][i][h] = l;
                mx[h] = fmaxf(mx[h], l);
            }
        }
        #pragma unroll
        for (int h = 0; h < 4; ++h)
            #pragma unroll
            for (int off = 32; off; off >>= 1) mx[h] = fmaxf(mx[h], __shfl_xor(mx[h], off));
        float sm[4] = {0.f, 0.f, 0.f, 0.f};
        for (int i = lane; i < cnt; i += 64) {
            #pragma unroll
            for (int h = 0; h < 4; ++h) {
                float ev = __expf(sh_alpha[w][i][h] - mx[h]);
                sh_alpha[w][i][h] = ev;
                sm[h] += ev;
            }
        }
        #pragma unroll
        for (int h = 0; h < 4; ++h)
            #pragma unroll
            for (int off = 32; off; off >>= 1) sm[h] += __shfl_xor(sm[h], off);
        float inv[4];
        #pragma unroll
        for (int h = 0; h < 4; ++h) inv[h] = 1.f / sm[h];

        // gather: lanes 0-31 even edges, lanes 32-63 odd edges; float4 per lane.
        // 4 rows in flight per lane (8 edges/iter) to cover L2 latency.
        const int coff = l32 * 4;
        float acc[4][4] = {};                      // [head][col]
        int i = 0;
        for (; i + 8 <= cnt; i += 8) {
            int i0 = i + half, i1 = i + 2 + half, i2 = i + 4 + half, i3 = i + 6 + half;
            int sg0 = sh_src[w][i0], sg1 = sh_src[w][i1];
            int sg2 = sh_src[w][i2], sg3 = sh_src[w][i3];
            float4 sv0 = *reinterpret_cast<const float4*>(&s[(size_t)sg0 * D + coff]);
            float4 sv1 = *reinterpret_cast<const float4*>(&s[(size_t)sg1 * D + coff]);
            float4 sv2 = *reinterpret_cast<const float4*>(&s[(size_t)sg2 * D + coff]);
            float4 sv3 = *reinterpret_cast<const float4*>(&s[(size_t)sg3 * D + coff]);
            float4 a0 = *reinterpret_cast<const float4*>(&sh_alpha[w][i0][0]);
            float4 a1 = *reinterpret_cast<const float4*>(&sh_alpha[w][i1][0]);
            float4 a2 = *reinterpret_cast<const float4*>(&sh_alpha[w][i2][0]);
            float4 a3 = *reinterpret_cast<const float4*>(&sh_alpha[w][i3][0]);
            float al0[4] = {a0.x, a0.y, a0.z, a0.w};
            float al1[4] = {a1.x, a1.y, a1.z, a1.w};
            float al2[4] = {a2.x, a2.y, a2.z, a2.w};
            float al3[4] = {a3.x, a3.y, a3.z, a3.w};
            float c0[4] = {sv0.x, sv0.y, sv0.z, sv0.w};
            float c1[4] = {sv1.x, sv1.y, sv1.z, sv1.w};
            float c2[4] = {sv2.x, sv2.y, sv2.z, sv2.w};
            float c3[4] = {sv3.x, sv3.y, sv3.z, sv3.w};
            #pragma unroll
            for (int h = 0; h < 4; ++h)
                #pragma unroll
                for (int c = 0; c < 4; ++c)
                    acc[h][c] += al0[h] * c0[c] + al1[h] * c1[c]
                               + al2[h] * c2[c] + al3[h] * c3[c];
        }
        for (; i < cnt; i += 2) {
            int ii = i + half;
            if (ii < cnt) {
                int sg = sh_src[w][ii];
                float4 sv = *reinterpret_cast<const float4*>(&s[(size_t)sg * D + coff]);
                float4 alv = *reinterpret_cast<const float4*>(&sh_alpha[w][ii][0]);
                float al[4] = {alv.x, alv.y, alv.z, alv.w};
                float cv[4] = {sv.x, sv.y, sv.z, sv.w};
                #pragma unroll
                for (int h = 0; h < 4; ++h)
                    #pragma unroll
                    for (int c = 0; c < 4; ++c) acc[h][c] += al[h] * cv[c];
            }
        }
        #pragma unroll
        for (int h = 0; h < 4; ++h)
            #pragma unroll
            for (int c = 0; c < 4; ++c) acc[h][c] += __shfl_xor(acc[h][c], 32);
        // write z fragments (split bf16) into LDS, A-frag-packed:
        // this lane owns heads {half*2, half*2+1}, cols coff..coff+3
        #pragma unroll
        for (int hh = 0; hh < 2; ++hh) {
            int h = half * 2 + hh;
            ushort4 zh, zl;
            float v0 = acc[h][0] * inv[h], v1 = acc[h][1] * inv[h];
            float v2 = acc[h][2] * inv[h], v3 = acc[h][3] * inv[h];
            zh.x = f2bf(v0); zh.y = f2bf(v1); zh.z = f2bf(v2); zh.w = f2bf(v3);
            zl.x = f2bf(v0 - bf2f(zh.x)); zl.y = f2bf(v1 - bf2f(zh.y));
            zl.z = f2bf(v2 - bf2f(zh.z)); zl.w = f2bf(v3 - bf2f(zh.w));
            const int kstep = h * 4 + (l32 >> 3);
            const int slot  = (l32 >> 1) & 3;
            const int jo    = (l32 & 1) * 4;
            const int off   = (slot * 16 + r) * 8 + jo;
            *reinterpret_cast<ushort4*>(&zf[0][kstep][off]) = zh;
            *reinterpret_cast<ushort4*>(&zf[1][kstep][off]) = zl;
        }
    }
    __syncthreads();

    // ---- MFMA phase: wave w -> 16-col tile ct = w ----
    f32x4 acc = {0.f, 0.f, 0.f, 0.f};
    const unsigned short* pb = p_hi + ((size_t)w * 16 * 64 + lane) * 8;
    const unsigned short* pl = p_lo + ((size_t)w * 16 * 64 + lane) * 8;
    #pragma unroll
    for (int ks = 0; ks < 16; ++ks) {
        s16x8 ah = *reinterpret_cast<const s16x8*>(&zf[0][ks][lane * 8]);
        s16x8 al = *reinterpret_cast<const s16x8*>(&zf[1][ks][lane * 8]);
        s16x8 bh = *reinterpret_cast<const s16x8*>(pb + ks * 512);
        s16x8 bl = *reinterpret_cast<const s16x8*>(pl + ks * 512);
        acc = __builtin_amdgcn_mfma_f32_16x16x32_bf16(ah, bh, acc, 0, 0, 0);
        acc = __builtin_amdgcn_mfma_f32_16x16x32_bf16(ah, bl, acc, 0, 0, 0);
        acc = __builtin_amdgcn_mfma_f32_16x16x32_bf16(al, bh, acc, 0, 0, 0);
    }
    // C/D layout: col = lane&15, row = (lane>>4)*4 + reg
    const int ocol = w * 16 + (lane & 15);
    const int orow = tile * 16 + (lane >> 4) * 4;
    const float cb = cvec[ocol];
    #pragma unroll
    for (int r2 = 0; r2 < 4; ++r2)
        out[(size_t)(orow + r2) * D + ocol] = acc[r2] + cb;
}

extern "C" void kernel_launch(void* const* d_in, const int* in_sizes, int n_in,
                              void* d_out, int out_size, void* d_ws, size_t ws_size,
                              hipStream_t stream) {
    const float* s       = (const float*)d_in[0];
    const int*   ei      = (const int*)d_in[1];
    const float* W       = (const float*)d_in[2];
    const float* att_src = (const float*)d_in[3];
    const float* att_dst = (const float*)d_in[4];
    const float* bias    = (const float*)d_in[5];
    const float* Wo      = (const float*)d_in[6];
    const float* bo      = (const float*)d_in[7];
    float* out = (float*)d_out;

    char* ws = (char*)d_ws;
    float* w_src = (float*)ws; ws += 512 * 4;
    float* w_dst = (float*)ws; ws += 512 * 4;
    float* a_src = (float*)ws; ws += (size_t)N * H * 4;
    float* a_dst = (float*)ws; ws += (size_t)N * H * 4;
    float* cvec  = (float*)ws; ws += 512;
    unsigned short* p_hi = (unsigned short*)ws; ws += (size_t)D * HC * 2;
    unsigned short* p_lo = (unsigned short*)ws; ws += (size_t)D * HC * 2;
    int* cursor = (int*)ws; ws += SEQ * 4;
    int* csr0   = (int*)ws; ws += (size_t)SEQ * SLOTS * 4;

    prep_all<<<394, 256, 0, stream>>>(W, att_src, att_dst, bias, Wo, bo,
                                      w_src, w_dst, p_hi, p_lo, cvec, cursor);
    att_fill<<<N / 4, 256, 0, stream>>>(s, w_src, w_dst, ei, a_src, a_dst, cursor, csr0);
    agg_out<<<N / 16, 512, 0, stream>>>(cursor, csr0, a_src, a_dst, s,
                                        p_hi, p_lo, cvec, out);
}